// Round 1
// baseline (166.987 us; speedup 1.0000x reference)
//
#include <hip/hip_runtime.h>

#define NODES 255
#define LEAVES 256
#define IN_DIM 512
#define ODIM 64
#define BM 64

typedef __attribute__((ext_vector_type(8))) short short8v;
typedef __attribute__((ext_vector_type(4))) float f32x4;
typedef __attribute__((ext_vector_type(4))) float f4v;
typedef unsigned short u16;
typedef unsigned int u32;

__device__ __forceinline__ u16 f32_bf16(float f) {
  u32 u = __builtin_bit_cast(u32, f);
  u += 0x7FFFu + ((u >> 16) & 1u);
  return (u16)(u >> 16);
}
__device__ __forceinline__ float bf16_f32(u16 h) {
  u32 u = ((u32)h) << 16;
  return __builtin_bit_cast(float, u);
}

// Pre-split layers (W) and action_probs^T into bf16 hi/lo pairs in workspace.
// W padded to 256 rows (row 255 = 0). AT is transposed: AT[j][leaf].
__global__ __launch_bounds__(256) void prep_kernel(
    const float* __restrict__ layers, const float* __restrict__ aprobs,
    u16* __restrict__ Wh, u16* __restrict__ Wl,
    u16* __restrict__ ATh, u16* __restrict__ ATl) {
  int id = blockIdx.x * 256 + threadIdx.x;
  if (id < LEAVES * IN_DIM) {
    int n = id >> 9;
    float v = (n < NODES) ? layers[id] : 0.f;
    u16 h = f32_bf16(v);
    Wh[id] = h;
    Wl[id] = f32_bf16(v - bf16_f32(h));
  } else if (id < LEAVES * IN_DIM + LEAVES * ODIM) {
    int t = id - LEAVES * IN_DIM;
    int l = t >> 6, j = t & 63;
    float v = aprobs[t];
    u16 h = f32_bf16(v);
    ATh[j * 256 + l] = h;
    ATl[j * 256 + l] = f32_bf16(v - bf16_f32(h));
  }
}

// Fused: z=x@W^T (split-bf16 MFMA) -> sigmoid -> tree leaf probs ->
// p@A (split-bf16 MFMA) -> softmax.
// Block: 512 threads (8 waves), BM=64 batch rows.
__global__ __launch_bounds__(512, 2) void prolo_main(
    const float* __restrict__ x, const float* __restrict__ comp,
    const float* __restrict__ alpha,
    const u16* __restrict__ Wh, const u16* __restrict__ Wl,
    const u16* __restrict__ ATh, const u16* __restrict__ ATl,
    float* __restrict__ out) {
  __shared__ float s_lds[BM * 256];   // 64 KB sigmoids, col XOR-swizzled by ((row>>2)&3)<<4
  __shared__ u16 ph[BM * 256];        // 16 KB p hi, elem XOR-swizzled by ((row&7)<<3)
  __shared__ u16 pl[BM * 256];        // 16 KB p lo
  __shared__ float c_s[256];

  const int tid = threadIdx.x;
  const int lane = tid & 63;
  const int w = tid >> 6;
  const int l15 = lane & 15;
  const int lq = lane >> 4;
  const int row0 = blockIdx.x * BM;

  if (tid < 256) c_s[tid] = (tid < NODES) ? comp[tid] : 0.f;
  __syncthreads();

  const float alphav = alpha[0];

  // ---- Phase 1: z MFMA. wave w: m-tile (w&3) = rows 16*(w&3)..+15, n-half (w>>2).
  const int mi = w & 3;
  const int nh = w >> 2;

  f32x4 acc[8];
#pragma unroll
  for (int i = 0; i < 8; ++i) acc[i] = {0.f, 0.f, 0.f, 0.f};

  const float* xp = x + (size_t)(row0 + (mi << 4) + l15) * IN_DIM + (lq << 3);

  for (int ks = 0; ks < 16; ++ks) {
    const float* ap = xp + (ks << 5);
    f4v a0 = *reinterpret_cast<const f4v*>(ap);
    f4v a1 = *reinterpret_cast<const f4v*>(ap + 4);
    short8v ah, al;
#pragma unroll
    for (int j = 0; j < 4; ++j) {
      float v = a0[j];
      u16 h = f32_bf16(v);
      ah[j] = (short)h;
      al[j] = (short)f32_bf16(v - bf16_f32(h));
      float v2 = a1[j];
      u16 h2 = f32_bf16(v2);
      ah[4 + j] = (short)h2;
      al[4 + j] = (short)f32_bf16(v2 - bf16_f32(h2));
    }
    const int koff = (ks << 5) + (lq << 3);
#pragma unroll
    for (int nt = 0; nt < 8; ++nt) {
      const int node = (nh << 7) + (nt << 4) + l15;
      const short8v bh = *reinterpret_cast<const short8v*>(Wh + ((size_t)node << 9) + koff);
      const short8v bl = *reinterpret_cast<const short8v*>(Wl + ((size_t)node << 9) + koff);
      acc[nt] = __builtin_amdgcn_mfma_f32_16x16x32_bf16(ah, bh, acc[nt], 0, 0, 0);
      acc[nt] = __builtin_amdgcn_mfma_f32_16x16x32_bf16(ah, bl, acc[nt], 0, 0, 0);
      acc[nt] = __builtin_amdgcn_mfma_f32_16x16x32_bf16(al, bh, acc[nt], 0, 0, 0);
    }
  }

  // ---- Phase 2: sigmoid(z - c) -> s_lds. D layout: col=lane&15, row=4*(lane>>4)+reg.
#pragma unroll
  for (int nt = 0; nt < 8; ++nt) {
    const int col = (nh << 7) + (nt << 4) + l15;
    const float cv = c_s[col];
#pragma unroll
    for (int r4 = 0; r4 < 4; ++r4) {
      const int row = (mi << 4) + (lq << 2) + r4;  // (row>>2)&3 == lq
      const float zv = (acc[nt][r4] - cv) * alphav;
      const float sv = 1.f / (1.f + expf(-zv));
      s_lds[(row << 8) + (col ^ (lq << 4))] = sv;
    }
  }
  __syncthreads();

  // ---- Phase 3: leaf probabilities. Thread = leaf-pair (2lp,2lp+1), 16 rows each.
  // Adjacent leaves share all 8 ancestors; differ only in the last turn.
  {
    const int lp = tid & 127;
    const int rg = tid >> 7;
    int anc[7], rbit[7];
#pragma unroll
    for (int n = 0; n < 7; ++n) {
      anc[n] = (1 << n) - 1 + ((2 * lp) >> (8 - n));
      rbit[n] = ((2 * lp) >> (7 - n)) & 1;
    }
    const int anc7 = 127 + lp;
    u32* phd = reinterpret_cast<u32*>(ph);
    u32* pld = reinterpret_cast<u32*>(pl);
    for (int rr = 0; rr < 16; ++rr) {
      const int r = (rg << 4) + rr;
      const int sw = ((r >> 2) & 3) << 4;
      const float* srow = s_lds + (r << 8);
      float pc = 1.f;
#pragma unroll
      for (int n = 0; n < 7; ++n) {
        const float sv = srow[anc[n] ^ sw];
        pc *= rbit[n] ? (1.f - sv) : sv;
      }
      const float s7 = srow[anc7 ^ sw];
      const float p0 = pc * s7;
      const float p1 = pc * (1.f - s7);
      const u16 h0 = f32_bf16(p0);
      const u16 lo0 = f32_bf16(p0 - bf16_f32(h0));
      const u16 h1 = f32_bf16(p1);
      const u16 lo1 = f32_bf16(p1 - bf16_f32(h1));
      // elem index pair base = 2lp ^ ((r&7)<<3) -> dword index = lp ^ ((r&7)<<2)
      const int di = (r << 7) + (lp ^ ((r & 7) << 2));
      phd[di] = (u32)h0 | ((u32)h1 << 16);
      pld[di] = (u32)lo0 | ((u32)lo1 << 16);
    }
  }
  __syncthreads();

  // ---- Phase 4: actions = p @ A (M=64,N=64,K=256), waves 0-3 only.
  if (w < 4) {
    f32x4 acc2[4];
#pragma unroll
    for (int i = 0; i < 4; ++i) acc2[i] = {0.f, 0.f, 0.f, 0.f};
    const int prow = (w << 4) + l15;
    const int psw = (prow & 7) << 3;
    for (int ks = 0; ks < 8; ++ks) {
      const int kb = (ks << 5) + (lq << 3);
      const int eb = kb ^ psw;  // swizzled, still 8-aligned
      const short8v pah = *reinterpret_cast<const short8v*>(ph + (prow << 8) + eb);
      const short8v pal = *reinterpret_cast<const short8v*>(pl + (prow << 8) + eb);
#pragma unroll
      for (int nt = 0; nt < 4; ++nt) {
        const int j = (nt << 4) + l15;
        const short8v bh = *reinterpret_cast<const short8v*>(ATh + (j << 8) + kb);
        const short8v bl = *reinterpret_cast<const short8v*>(ATl + (j << 8) + kb);
        acc2[nt] = __builtin_amdgcn_mfma_f32_16x16x32_bf16(pah, bh, acc2[nt], 0, 0, 0);
        acc2[nt] = __builtin_amdgcn_mfma_f32_16x16x32_bf16(pah, bl, acc2[nt], 0, 0, 0);
        acc2[nt] = __builtin_amdgcn_mfma_f32_16x16x32_bf16(pal, bh, acc2[nt], 0, 0, 0);
      }
    }
    // ---- Phase 5: softmax over 64 cols (16 lanes x 4 tiles per row), store.
#pragma unroll
    for (int r4 = 0; r4 < 4; ++r4) {
      const int row = (w << 4) + (lq << 2) + r4;
      float v0 = acc2[0][r4], v1 = acc2[1][r4], v2 = acc2[2][r4], v3 = acc2[3][r4];
      float m = fmaxf(fmaxf(v0, v1), fmaxf(v2, v3));
#pragma unroll
      for (int d = 1; d < 16; d <<= 1) m = fmaxf(m, __shfl_xor(m, d, 64));
      float e0 = expf(v0 - m), e1 = expf(v1 - m), e2 = expf(v2 - m), e3 = expf(v3 - m);
      float sum = e0 + e1 + e2 + e3;
#pragma unroll
      for (int d = 1; d < 16; d <<= 1) sum += __shfl_xor(sum, d, 64);
      const float inv = 1.f / sum;
      float* op = out + (size_t)(row0 + row) * ODIM + l15;
      op[0]  = e0 * inv;
      op[16] = e1 * inv;
      op[32] = e2 * inv;
      op[48] = e3 * inv;
    }
  }
}

extern "C" void kernel_launch(void* const* d_in, const int* in_sizes, int n_in,
                              void* d_out, int out_size, void* d_ws, size_t ws_size,
                              hipStream_t stream) {
  const float* x      = (const float*)d_in[0];
  const float* layers = (const float*)d_in[1];
  const float* comp   = (const float*)d_in[2];
  const float* alpha  = (const float*)d_in[3];
  const float* aprobs = (const float*)d_in[4];
  float* out = (float*)d_out;

  const size_t wsplit = (size_t)LEAVES * IN_DIM;  // 131072 elems per half
  const size_t atsz   = (size_t)LEAVES * ODIM;    // 16384 elems per half
  if (ws_size < (2 * wsplit + 2 * atsz) * sizeof(u16)) return;  // 589,824 B needed

  u16* Wh  = (u16*)d_ws;
  u16* Wl  = Wh + wsplit;
  u16* ATh = Wl + wsplit;
  u16* ATl = ATh + atsz;

  const int prep_items = LEAVES * IN_DIM + LEAVES * ODIM;
  prep_kernel<<<dim3((prep_items + 255) / 256), dim3(256), 0, stream>>>(
      layers, aprobs, Wh, Wl, ATh, ATl);

  prolo_main<<<dim3(32768 / BM), dim3(512), 0, stream>>>(
      x, comp, alpha, Wh, Wl, ATh, ATl, out);
}

// Round 2
// 64.986 us; speedup vs baseline: 2.5696x; 2.5696x over previous
//
#include <hip/hip_runtime.h>

#define NODES 255
#define IN_DIM 512
#define ODIM 64
#define BM 64

typedef __attribute__((ext_vector_type(8))) short short8v;
typedef __attribute__((ext_vector_type(4))) float f32x4;
typedef unsigned short u16;
typedef unsigned int u32;

__device__ __forceinline__ u16 f32_bf16(float f) {
  u32 u = __builtin_bit_cast(u32, f);
  u += 0x7FFFu + ((u >> 16) & 1u);
  return (u16)(u >> 16);
}
__device__ __forceinline__ float bf16_f32(u16 h) {
  u32 u = ((u32)h) << 16;
  return __builtin_bit_cast(float, u);
}

// Pre-split layers (W) and action_probs^T into bf16 hi/lo pairs in workspace.
// W padded to 256 rows (row 255 = 0). AT is transposed: AT[j][leaf].
__global__ __launch_bounds__(256) void prep_kernel(
    const float* __restrict__ layers, const float* __restrict__ aprobs,
    u16* __restrict__ Wh, u16* __restrict__ Wl,
    u16* __restrict__ ATh, u16* __restrict__ ATl) {
  int id = blockIdx.x * 256 + threadIdx.x;
  if (id < 256 * IN_DIM) {
    int n = id >> 9;
    float v = (n < NODES) ? layers[id] : 0.f;
    u16 h = f32_bf16(v);
    Wh[id] = h;
    Wl[id] = f32_bf16(v - bf16_f32(h));
  } else if (id < 256 * IN_DIM + 256 * ODIM) {
    int t = id - 256 * IN_DIM;
    int l = t >> 6, j = t & 63;
    float v = aprobs[t];
    u16 h = f32_bf16(v);
    ATh[j * 256 + l] = h;
    ATl[j * 256 + l] = f32_bf16(v - bf16_f32(h));
  }
}

// Fused: z=x@W^T (split-bf16 MFMA, x LDS-staged, W dedup'd per-wave) ->
// sigmoid -> in-register tree leaf probs -> p@A (K-split) -> softmax.
// 512 threads (8 waves), BM=64 rows/block, LDS 72KB -> 2 blocks/CU.
__global__ __launch_bounds__(512, 4) void prolo_main(
    const float* __restrict__ x, const float* __restrict__ comp,
    const float* __restrict__ alpha,
    const u16* __restrict__ Wh, const u16* __restrict__ Wl,
    const u16* __restrict__ ATh, const u16* __restrict__ ATl,
    float* __restrict__ out) {
  __shared__ float s_sig[BM * 256];  // 64 KB sigmoids, col ^ (row&15) swizzle; reused for partials
  __shared__ u16 sAh[BM * 32];       // 4 KB x-chunk hi (k ^ ((row&3)<<3) swizzle)
  __shared__ u16 sAl[BM * 32];       // 4 KB x-chunk lo

  const int tid = threadIdx.x;
  const int lane = tid & 63;
  const int w = tid >> 6;
  const int l15 = lane & 15;
  const int lq = lane >> 4;
  const int row0 = blockIdx.x * BM;
  const float alphav = alpha[0];

  // ---------- Phase 1: z GEMM. Wave w owns nodes [32w, 32w+32), all 64 rows.
  f32x4 acc[4][2];
#pragma unroll
  for (int i = 0; i < 4; ++i)
#pragma unroll
    for (int j = 0; j < 2; ++j) acc[i][j] = {0.f, 0.f, 0.f, 0.f};

  const int srow_t = tid >> 3;          // staging: row 0..63
  const int scol_t = (tid & 7) << 2;    // staging: 4 floats at col 0..28
  const int soff = srow_t * 32 + (scol_t ^ ((srow_t & 3) << 3));
  const float* xbase = x + (size_t)(row0 + srow_t) * IN_DIM + scol_t;

  f32x4 v = *reinterpret_cast<const f32x4*>(xbase);  // chunk 0

  for (int ks = 0; ks < 16; ++ks) {
    // convert current chunk to bf16 hi/lo, store to LDS (swizzled)
    {
      u16 h0 = f32_bf16(v[0]), h1 = f32_bf16(v[1]), h2 = f32_bf16(v[2]), h3 = f32_bf16(v[3]);
      u16 lo0 = f32_bf16(v[0] - bf16_f32(h0)), lo1 = f32_bf16(v[1] - bf16_f32(h1));
      u16 lo2 = f32_bf16(v[2] - bf16_f32(h2)), lo3 = f32_bf16(v[3] - bf16_f32(h3));
      u32* dph = reinterpret_cast<u32*>(sAh + soff);
      dph[0] = (u32)h0 | ((u32)h1 << 16);
      dph[1] = (u32)h2 | ((u32)h3 << 16);
      u32* dpl = reinterpret_cast<u32*>(sAl + soff);
      dpl[0] = (u32)lo0 | ((u32)lo1 << 16);
      dpl[1] = (u32)lo2 | ((u32)lo3 << 16);
    }
    __syncthreads();

    if (ks < 15) v = *reinterpret_cast<const f32x4*>(xbase + (ks + 1) * 32);  // prefetch

    const int kglob = (ks << 5) + (lq << 3);
    short8v bh[2], bl[2];
#pragma unroll
    for (int ntl = 0; ntl < 2; ++ntl) {
      const int node = (w << 5) + (ntl << 4) + l15;
      bh[ntl] = *reinterpret_cast<const short8v*>(Wh + ((size_t)node << 9) + kglob);
      bl[ntl] = *reinterpret_cast<const short8v*>(Wl + ((size_t)node << 9) + kglob);
    }
#pragma unroll
    for (int mt = 0; mt < 4; ++mt) {
      const int r = (mt << 4) + l15;
      const int aoff = r * 32 + ((lq << 3) ^ ((r & 3) << 3));
      const short8v ah = *reinterpret_cast<const short8v*>(sAh + aoff);
      const short8v al = *reinterpret_cast<const short8v*>(sAl + aoff);
#pragma unroll
      for (int ntl = 0; ntl < 2; ++ntl) {
        acc[mt][ntl] = __builtin_amdgcn_mfma_f32_16x16x32_bf16(ah, bh[ntl], acc[mt][ntl], 0, 0, 0);
        acc[mt][ntl] = __builtin_amdgcn_mfma_f32_16x16x32_bf16(ah, bl[ntl], acc[mt][ntl], 0, 0, 0);
        acc[mt][ntl] = __builtin_amdgcn_mfma_f32_16x16x32_bf16(al, bh[ntl], acc[mt][ntl], 0, 0, 0);
      }
    }
    __syncthreads();
  }

  // ---------- Phase 2: sigmoid((z-c)*alpha) -> s_sig (swizzled)
#pragma unroll
  for (int ntl = 0; ntl < 2; ++ntl) {
    const int col = (w << 5) + (ntl << 4) + l15;
    const float cv = (col < NODES) ? comp[col] : 0.f;
#pragma unroll
    for (int mt = 0; mt < 4; ++mt) {
#pragma unroll
      for (int r4 = 0; r4 < 4; ++r4) {
        const int r = (mt << 4) + (lq << 2) + r4;
        const float z = (acc[mt][ntl][r4] - cv) * alphav;
        const float s = 1.f / (1.f + __expf(-z));
        s_sig[(r << 8) + (col ^ (r & 15))] = s;
      }
    }
  }
  __syncthreads();

  // ---------- Phase 3+4: in-register leaf probs feeding p@A MFMA.
  // Wave w: m-tile mt = w&3 (rows mt*16..+15), K-half kh = w>>2 (128 leaves).
  const int mt = w & 3;
  const int kh = w >> 2;
  const int arow = (mt << 4) + l15;
  const float* srow = s_sig + (arow << 8);
  const int sw = arow & 15;

  f32x4 acc2[4];
#pragma unroll
  for (int i = 0; i < 4; ++i) acc2[i] = {0.f, 0.f, 0.f, 0.f};

#pragma unroll
  for (int ks = 0; ks < 4; ++ks) {
    const int lb = (kh << 7) + (ks << 5) + (lq << 3);  // 8-aligned leaf base
    // shared prefix: levels 0..4 (node and direction shared across the 8 leaves)
    float P = 1.f;
#pragma unroll
    for (int n = 0; n < 5; ++n) {
      const int node = (1 << n) - 1 + (lb >> (8 - n));
      const float s = srow[node ^ sw];
      P *= ((lb >> (7 - n)) & 1) ? (1.f - s) : s;
    }
    const float s5 = srow[(31 + (lb >> 3)) ^ sw];     // level-5 node shared, direction varies
    const int n6 = 63 + (lb >> 2);
    const float s6a = srow[n6 ^ sw];
    const float s6b = srow[(n6 + 1) ^ sw];
    const int n7 = 127 + (lb >> 1);
    const float s7_0 = srow[n7 ^ sw];
    const float s7_1 = srow[(n7 + 1) ^ sw];
    const float s7_2 = srow[(n7 + 2) ^ sw];
    const float s7_3 = srow[(n7 + 3) ^ sw];
    const float q0 = P * s5, q1 = P - P * s5;
    const float r00 = q0 * s6a, r01 = q0 - q0 * s6a;
    const float r10 = q1 * s6b, r11 = q1 - q1 * s6b;
    float p[8];
    p[0] = r00 * s7_0; p[1] = r00 - p[0];
    p[2] = r01 * s7_1; p[3] = r01 - p[2];
    p[4] = r10 * s7_2; p[5] = r10 - p[4];
    p[6] = r11 * s7_3; p[7] = r11 - p[6];
    short8v pah, pal;
#pragma unroll
    for (int j = 0; j < 8; ++j) {
      const u16 h = f32_bf16(p[j]);
      pah[j] = (short)h;
      pal[j] = (short)f32_bf16(p[j] - bf16_f32(h));
    }
#pragma unroll
    for (int nt = 0; nt < 4; ++nt) {
      const int c = (nt << 4) + l15;
      const short8v bhv = *reinterpret_cast<const short8v*>(ATh + (c << 8) + lb);
      const short8v blv = *reinterpret_cast<const short8v*>(ATl + (c << 8) + lb);
      acc2[nt] = __builtin_amdgcn_mfma_f32_16x16x32_bf16(pah, bhv, acc2[nt], 0, 0, 0);
      acc2[nt] = __builtin_amdgcn_mfma_f32_16x16x32_bf16(pah, blv, acc2[nt], 0, 0, 0);
      acc2[nt] = __builtin_amdgcn_mfma_f32_16x16x32_bf16(pal, bhv, acc2[nt], 0, 0, 0);
    }
  }
  __syncthreads();  // all waves done reading s_sig

  // K-half combine: kh=1 dumps partials into (now free) s_sig, kh=0 finalizes.
  float* part = s_sig;  // [64][64] f32, 16 KB
  if (kh == 1) {
#pragma unroll
    for (int nt = 0; nt < 4; ++nt)
#pragma unroll
      for (int r4 = 0; r4 < 4; ++r4)
        part[(((mt << 4) + (lq << 2) + r4) << 6) + (nt << 4) + l15] = acc2[nt][r4];
  }
  __syncthreads();

  if (kh == 0) {
#pragma unroll
    for (int r4 = 0; r4 < 4; ++r4) {
      const int rloc = (mt << 4) + (lq << 2) + r4;
      float v0 = acc2[0][r4] + part[(rloc << 6) + l15];
      float v1 = acc2[1][r4] + part[(rloc << 6) + 16 + l15];
      float v2 = acc2[2][r4] + part[(rloc << 6) + 32 + l15];
      float v3 = acc2[3][r4] + part[(rloc << 6) + 48 + l15];
      float m = fmaxf(fmaxf(v0, v1), fmaxf(v2, v3));
#pragma unroll
      for (int d = 1; d < 16; d <<= 1) m = fmaxf(m, __shfl_xor(m, d, 64));
      float e0 = __expf(v0 - m), e1 = __expf(v1 - m), e2 = __expf(v2 - m), e3 = __expf(v3 - m);
      float ssum = e0 + e1 + e2 + e3;
#pragma unroll
      for (int d = 1; d < 16; d <<= 1) ssum += __shfl_xor(ssum, d, 64);
      const float inv = 1.f / ssum;
      float* op = out + (size_t)(row0 + rloc) * ODIM + l15;
      op[0] = e0 * inv;
      op[16] = e1 * inv;
      op[32] = e2 * inv;
      op[48] = e3 * inv;
    }
  }
}

extern "C" void kernel_launch(void* const* d_in, const int* in_sizes, int n_in,
                              void* d_out, int out_size, void* d_ws, size_t ws_size,
                              hipStream_t stream) {
  const float* x      = (const float*)d_in[0];
  const float* layers = (const float*)d_in[1];
  const float* comp   = (const float*)d_in[2];
  const float* alpha  = (const float*)d_in[3];
  const float* aprobs = (const float*)d_in[4];
  float* out = (float*)d_out;

  const size_t wsplit = (size_t)256 * IN_DIM;  // 131072 elems per half
  const size_t atsz   = (size_t)256 * ODIM;    // 16384 elems per half
  if (ws_size < (2 * wsplit + 2 * atsz) * sizeof(u16)) return;  // 589,824 B needed

  u16* Wh  = (u16*)d_ws;
  u16* Wl  = Wh + wsplit;
  u16* ATh = Wl + wsplit;
  u16* ATl = ATh + atsz;

  const int prep_items = 256 * IN_DIM + 256 * ODIM;
  prep_kernel<<<dim3((prep_items + 255) / 256), dim3(256), 0, stream>>>(
      layers, aprobs, Wh, Wl, ATh, ATl);

  prolo_main<<<dim3(32768 / BM), dim3(512), 0, stream>>>(
      x, comp, alpha, Wh, Wl, ATh, ATl, out);
}

// Round 3
// 62.068 us; speedup vs baseline: 2.6904x; 1.0470x over previous
//
#include <hip/hip_runtime.h>

#define NODES 255
#define IN_DIM 512
#define ODIM 64
#define BM 64
#define BK 64

typedef __attribute__((ext_vector_type(8))) short short8v;
typedef __attribute__((ext_vector_type(4))) float f32x4;
typedef unsigned short u16;
typedef unsigned int u32;

__device__ __forceinline__ u16 f32_bf16(float f) {
  u32 u = __builtin_bit_cast(u32, f);
  u += 0x7FFFu + ((u >> 16) & 1u);
  return (u16)(u >> 16);
}
__device__ __forceinline__ float bf16_f32(u16 h) {
  u32 u = ((u32)h) << 16;
  return __builtin_bit_cast(float, u);
}

// Pre-split layers (W) and action_probs^T into bf16 hi/lo pairs in workspace.
__global__ __launch_bounds__(256) void prep_kernel(
    const float* __restrict__ layers, const float* __restrict__ aprobs,
    u16* __restrict__ Wh, u16* __restrict__ Wl,
    u16* __restrict__ ATh, u16* __restrict__ ATl) {
  int id = blockIdx.x * 256 + threadIdx.x;
  if (id < 256 * IN_DIM) {
    int n = id >> 9;
    float v = (n < NODES) ? layers[id] : 0.f;
    u16 h = f32_bf16(v);
    Wh[id] = h;
    Wl[id] = f32_bf16(v - bf16_f32(h));
  } else if (id < 256 * IN_DIM + 256 * ODIM) {
    int t = id - 256 * IN_DIM;
    int l = t >> 6, j = t & 63;
    float v = aprobs[t];
    u16 h = f32_bf16(v);
    ATh[j * 256 + l] = h;
    ATl[j * 256 + l] = f32_bf16(v - bf16_f32(h));
  }
}

// 512 threads (8 waves), BM=64 rows/block. LDS: 64KB union
//   phase 1: x-chunk double-buffer bf16 hi/lo [2][2][64][64] (32KB)
//   phase 2+: s_sig f32[64][256] (64KB), phase 4: partials f32[64][64]
__global__ __launch_bounds__(512, 4) void prolo_main(
    const float* __restrict__ x, const float* __restrict__ comp,
    const float* __restrict__ alpha,
    const u16* __restrict__ Wh, const u16* __restrict__ Wl,
    const u16* __restrict__ ATh, const u16* __restrict__ ATl,
    float* __restrict__ out) {
  __shared__ __align__(16) unsigned char smem[65536];
  float* s_sig = (float*)smem;
  u16* sA = (u16*)smem;  // buf b: hi at b*8192, lo at b*8192+4096 (u16 units)

  const int tid = threadIdx.x;
  const int lane = tid & 63;
  const int w = tid >> 6;
  const int l15 = lane & 15;
  const int lq = lane >> 4;
  const int row0 = blockIdx.x * BM;
  const float alphav = alpha[0];

  // prefetch comparators for phase 2
  const int col0 = (w << 5) + l15;
  const int col1 = col0 + 16;
  const float cv0 = (col0 < NODES) ? comp[col0] : 0.f;
  const float cv1 = (col1 < NODES) ? comp[col1] : 0.f;

  // ---------- Phase 1: z GEMM. Wave w owns nodes [32w, 32w+32), all 64 rows.
  f32x4 acc[4][2];
#pragma unroll
  for (int i = 0; i < 4; ++i)
#pragma unroll
    for (int j = 0; j < 2; ++j) acc[i][j] = {0.f, 0.f, 0.f, 0.f};

  const int srow = tid >> 3;            // staging row 0..63
  const int k0 = (tid & 7) << 3;        // staging k 0..56
  const int soff = srow * 64 + (k0 ^ ((srow & 7) << 3));
  const float* xbase = x + (size_t)(row0 + srow) * IN_DIM + k0;

  // 2-deep register prefetch (chunk = 64 k-columns; 8 floats/thread)
  f32x4 vA0 = *reinterpret_cast<const f32x4*>(xbase);
  f32x4 vA1 = *reinterpret_cast<const f32x4*>(xbase + 4);
  f32x4 vB0 = *reinterpret_cast<const f32x4*>(xbase + 64);
  f32x4 vB1 = *reinterpret_cast<const f32x4*>(xbase + 68);

#define STAGE_CHUNK(P0, P1, BUF)                                              \
  {                                                                           \
    u32* dh = reinterpret_cast<u32*>(sA + (BUF)*8192 + soff);                 \
    u32* dl = reinterpret_cast<u32*>(sA + (BUF)*8192 + 4096 + soff);          \
    float ff[8] = {P0[0], P0[1], P0[2], P0[3], P1[0], P1[1], P1[2], P1[3]};   \
    _Pragma("unroll") for (int j = 0; j < 4; ++j) {                           \
      u16 ha = f32_bf16(ff[2 * j]), hb = f32_bf16(ff[2 * j + 1]);             \
      u16 la = f32_bf16(ff[2 * j] - bf16_f32(ha));                            \
      u16 lb = f32_bf16(ff[2 * j + 1] - bf16_f32(hb));                        \
      dh[j] = (u32)ha | ((u32)hb << 16);                                      \
      dl[j] = (u32)la | ((u32)lb << 16);                                      \
    }                                                                         \
  }

  STAGE_CHUNK(vA0, vA1, 0);  // chunk 0 -> buf 0
  __syncthreads();

#pragma unroll
  for (int ks = 0; ks < 8; ++ks) {
    // prefetch chunk ks+2 into the A-slot (its old data already staged)
    if (ks + 2 < 8) {
      const float* xp = xbase + (ks + 2) * 64;
      vA0 = *reinterpret_cast<const f32x4*>(xp);
      vA1 = *reinterpret_cast<const f32x4*>(xp + 4);
    }
    // stage chunk ks+1 (in B-slot) into buf[(ks+1)&1]
    if (ks + 1 < 8) STAGE_CHUNK(vB0, vB1, ((ks + 1) & 1));

    // MFMA on chunk ks from buf[ks&1]
    const int buf = ks & 1;
#pragma unroll
    for (int kq = 0; kq < 2; ++kq) {
      const int kglob = (ks << 6) + (kq << 5) + (lq << 3);
      short8v bh[2], bl[2];
#pragma unroll
      for (int ntl = 0; ntl < 2; ++ntl) {
        const int node = (w << 5) + (ntl << 4) + l15;
        bh[ntl] = *reinterpret_cast<const short8v*>(Wh + ((size_t)node << 9) + kglob);
        bl[ntl] = *reinterpret_cast<const short8v*>(Wl + ((size_t)node << 9) + kglob);
      }
#pragma unroll
      for (int mt = 0; mt < 4; ++mt) {
        const int r = (mt << 4) + l15;
        const int kk = (kq << 5) + (lq << 3);
        const int aoff = r * 64 + (kk ^ ((r & 7) << 3));
        const short8v ah = *reinterpret_cast<const short8v*>(sA + buf * 8192 + aoff);
        const short8v al = *reinterpret_cast<const short8v*>(sA + buf * 8192 + 4096 + aoff);
#pragma unroll
        for (int ntl = 0; ntl < 2; ++ntl) {
          acc[mt][ntl] = __builtin_amdgcn_mfma_f32_16x16x32_bf16(ah, bh[ntl], acc[mt][ntl], 0, 0, 0);
          acc[mt][ntl] = __builtin_amdgcn_mfma_f32_16x16x32_bf16(ah, bl[ntl], acc[mt][ntl], 0, 0, 0);
          acc[mt][ntl] = __builtin_amdgcn_mfma_f32_16x16x32_bf16(al, bh[ntl], acc[mt][ntl], 0, 0, 0);
        }
      }
    }
    // rotate register slots: B <- chunk ks+2
    {
      f32x4 t0 = vA0, t1 = vA1;
      vA0 = vB0; vA1 = vB1;
      vB0 = t0;  vB1 = t1;
    }
    __syncthreads();
  }

  // ---------- Phase 2: sigmoid((z-c)*alpha) -> s_sig (col ^ (row&15) swizzle)
#pragma unroll
  for (int ntl = 0; ntl < 2; ++ntl) {
    const int col = (w << 5) + (ntl << 4) + l15;
    const float cv = ntl ? cv1 : cv0;
#pragma unroll
    for (int mt = 0; mt < 4; ++mt) {
#pragma unroll
      for (int r4 = 0; r4 < 4; ++r4) {
        const int r = (mt << 4) + (lq << 2) + r4;
        const float z = (acc[mt][ntl][r4] - cv) * alphav;
        const float s = 1.f / (1.f + __expf(-z));
        s_sig[(r << 8) + (col ^ (r & 15))] = s;
      }
    }
  }
  __syncthreads();

  // ---------- Phase 3+4: in-register leaf probs feeding p@A MFMA.
  const int mt = w & 3;
  const int kh = w >> 2;
  const int arow = (mt << 4) + l15;
  const float* srow_p = s_sig + (arow << 8);
  const int sw = arow & 15;

  f32x4 acc2[4];
#pragma unroll
  for (int i = 0; i < 4; ++i) acc2[i] = {0.f, 0.f, 0.f, 0.f};

#pragma unroll
  for (int ks = 0; ks < 4; ++ks) {
    const int lb = (kh << 7) + (ks << 5) + (lq << 3);
    float P = 1.f;
#pragma unroll
    for (int n = 0; n < 5; ++n) {
      const int node = (1 << n) - 1 + (lb >> (8 - n));
      const float s = srow_p[node ^ sw];
      P *= ((lb >> (7 - n)) & 1) ? (1.f - s) : s;
    }
    const float s5 = srow_p[(31 + (lb >> 3)) ^ sw];
    const int n6 = 63 + (lb >> 2);
    const float s6a = srow_p[n6 ^ sw];
    const float s6b = srow_p[(n6 + 1) ^ sw];
    const int n7 = 127 + (lb >> 1);
    const float s7_0 = srow_p[n7 ^ sw];
    const float s7_1 = srow_p[(n7 + 1) ^ sw];
    const float s7_2 = srow_p[(n7 + 2) ^ sw];
    const float s7_3 = srow_p[(n7 + 3) ^ sw];
    const float q0 = P * s5, q1 = P - P * s5;
    const float r00 = q0 * s6a, r01 = q0 - q0 * s6a;
    const float r10 = q1 * s6b, r11 = q1 - q1 * s6b;
    float p[8];
    p[0] = r00 * s7_0; p[1] = r00 - p[0];
    p[2] = r01 * s7_1; p[3] = r01 - p[2];
    p[4] = r10 * s7_2; p[5] = r10 - p[4];
    p[6] = r11 * s7_3; p[7] = r11 - p[6];
    short8v pah, pal;
#pragma unroll
    for (int j = 0; j < 8; ++j) {
      const u16 h = f32_bf16(p[j]);
      pah[j] = (short)h;
      pal[j] = (short)f32_bf16(p[j] - bf16_f32(h));
    }
#pragma unroll
    for (int nt = 0; nt < 4; ++nt) {
      const int c = (nt << 4) + l15;
      const short8v bhv = *reinterpret_cast<const short8v*>(ATh + (c << 8) + lb);
      const short8v blv = *reinterpret_cast<const short8v*>(ATl + (c << 8) + lb);
      acc2[nt] = __builtin_amdgcn_mfma_f32_16x16x32_bf16(pah, bhv, acc2[nt], 0, 0, 0);
      acc2[nt] = __builtin_amdgcn_mfma_f32_16x16x32_bf16(pah, blv, acc2[nt], 0, 0, 0);
      acc2[nt] = __builtin_amdgcn_mfma_f32_16x16x32_bf16(pal, bhv, acc2[nt], 0, 0, 0);
    }
  }
  __syncthreads();  // all waves done reading s_sig

  // K-half combine via smem partials (aliases s_sig, now dead)
  float* part = (float*)smem;  // [64][64] f32
  if (kh == 1) {
#pragma unroll
    for (int nt = 0; nt < 4; ++nt)
#pragma unroll
      for (int r4 = 0; r4 < 4; ++r4)
        part[(((mt << 4) + (lq << 2) + r4) << 6) + (nt << 4) + l15] = acc2[nt][r4];
  }
  __syncthreads();

  if (kh == 0) {
#pragma unroll
    for (int r4 = 0; r4 < 4; ++r4) {
      const int rloc = (mt << 4) + (lq << 2) + r4;
      float v0 = acc2[0][r4] + part[(rloc << 6) + l15];
      float v1 = acc2[1][r4] + part[(rloc << 6) + 16 + l15];
      float v2 = acc2[2][r4] + part[(rloc << 6) + 32 + l15];
      float v3 = acc2[3][r4] + part[(rloc << 6) + 48 + l15];
      float m = fmaxf(fmaxf(v0, v1), fmaxf(v2, v3));
#pragma unroll
      for (int d = 1; d < 16; d <<= 1) m = fmaxf(m, __shfl_xor(m, d, 64));
      float e0 = __expf(v0 - m), e1 = __expf(v1 - m), e2 = __expf(v2 - m), e3 = __expf(v3 - m);
      float ssum = e0 + e1 + e2 + e3;
#pragma unroll
      for (int d = 1; d < 16; d <<= 1) ssum += __shfl_xor(ssum, d, 64);
      const float inv = 1.f / ssum;
      float* op = out + (size_t)(row0 + rloc) * ODIM + l15;
      op[0] = e0 * inv;
      op[16] = e1 * inv;
      op[32] = e2 * inv;
      op[48] = e3 * inv;
    }
  }
}

extern "C" void kernel_launch(void* const* d_in, const int* in_sizes, int n_in,
                              void* d_out, int out_size, void* d_ws, size_t ws_size,
                              hipStream_t stream) {
  const float* x      = (const float*)d_in[0];
  const float* layers = (const float*)d_in[1];
  const float* comp   = (const float*)d_in[2];
  const float* alpha  = (const float*)d_in[3];
  const float* aprobs = (const float*)d_in[4];
  float* out = (float*)d_out;

  const size_t wsplit = (size_t)256 * IN_DIM;
  const size_t atsz   = (size_t)256 * ODIM;
  if (ws_size < (2 * wsplit + 2 * atsz) * sizeof(u16)) return;

  u16* Wh  = (u16*)d_ws;
  u16* Wl  = Wh + wsplit;
  u16* ATh = Wl + wsplit;
  u16* ATl = ATh + atsz;

  const int prep_items = 256 * IN_DIM + 256 * ODIM;
  prep_kernel<<<dim3((prep_items + 255) / 256), dim3(256), 0, stream>>>(
      layers, aprobs, Wh, Wl, ATh, ATl);

  prolo_main<<<dim3(32768 / BM), dim3(512), 0, stream>>>(
      x, comp, alpha, Wh, Wl, ATh, ATl, out);
}